// Round 5
// baseline (250.989 us; speedup 1.0000x reference)
//
#include <hip/hip_runtime.h>
#include <stdint.h>

#define BT 128
#define NN 1024
#define FF 128

typedef __attribute__((ext_vector_type(8))) short short8;
typedef __attribute__((ext_vector_type(4))) float float4v;
typedef __attribute__((ext_vector_type(16))) float float16v;
typedef __attribute__((ext_vector_type(4))) unsigned short ushort4v;

__device__ __forceinline__ unsigned short f2bf(float f) {
  uint32_t u = __builtin_bit_cast(uint32_t, f);
  u += 0x7FFFu + ((u >> 16) & 1u);   // RNE
  return (unsigned short)(u >> 16);
}

__device__ __forceinline__ void gload16(const void* g, void* l) {
  __builtin_amdgcn_global_load_lds(
      (const __attribute__((address_space(1))) uint32_t*)(g),
      (__attribute__((address_space(3))) uint32_t*)(l),
      16, 0, 0);
}

// ---- fused: S -> Sbf + SbfT (blocks 0..63); W -> Wk2 (blocks 64..319) ------
__global__ __launch_bounds__(256) void k_cvt_sw(const float* __restrict__ S,
                                                unsigned short* __restrict__ Sbf,
                                                unsigned short* __restrict__ SbfT,
                                                const float* __restrict__ W,
                                                unsigned short* __restrict__ Wk2) {
  __shared__ unsigned short tile[128 * 132];
  int tid = threadIdx.x;
  if (blockIdx.x >= 64) {
    int gid = (blockIdx.x - 64) * 256 + tid;
    int k = gid >> 14, o = (gid >> 7) & 127, f = gid & 127;
    Wk2[gid] = f2bf(W[(o * 128 + f) * 4 + k]);
    return;
  }
  int r0 = ((int)blockIdx.x >> 3) << 7;
  int c0 = ((int)blockIdx.x & 7) << 7;
#pragma unroll
  for (int i = 0; i < 16; ++i) {
    int idx = i * 256 + tid;          // 4096 float4s
    int r = idx >> 5, cq = idx & 31;
    float4v v = reinterpret_cast<const float4v*>(S)[(size_t)(r0 + r) * 256 + (c0 >> 2) + cq];
    ushort4v h;
    h[0] = f2bf(v[0]); h[1] = f2bf(v[1]); h[2] = f2bf(v[2]); h[3] = f2bf(v[3]);
    *reinterpret_cast<ushort4v*>(&Sbf[(size_t)(r0 + r) * 1024 + c0 + cq * 4]) = h;
    *reinterpret_cast<ushort4v*>(&tile[r * 132 + cq * 4]) = h;
  }
  __syncthreads();
#pragma unroll
  for (int i = 0; i < 16; ++i) {
    int idx = i * 256 + tid;          // 4096 packs
    int c = idx >> 5, rq = idx & 31;
    ushort4v h;
#pragma unroll
    for (int j = 0; j < 4; ++j) h[j] = tile[(rq * 4 + j) * 132 + c];
    *reinterpret_cast<ushort4v*>(&SbfT[(size_t)(c0 + c) * 1024 + r0 + rq * 4]) = h;
  }
}

// X fp32 [bt][n][f] -> Xbf bf16 same layout, Xt bf16 [bt][f][n]
__global__ __launch_bounds__(256) void k_cvt_x(const float* __restrict__ X,
                                               unsigned short* __restrict__ Xbf,
                                               unsigned short* __restrict__ Xt) {
  __shared__ unsigned short tile[128 * 132];
  int bt = blockIdx.x >> 3;
  int n0 = (blockIdx.x & 7) << 7;
  int tid = threadIdx.x;
  size_t base = ((size_t)bt * NN + n0) * FF;
#pragma unroll
  for (int i = 0; i < 16; ++i) {
    int idx = i * 256 + tid;
    int e = idx * 4;
    int n = e >> 7, f = e & 127;
    float4v v = reinterpret_cast<const float4v*>(X + base)[idx];
    ushort4v h;
    h[0] = f2bf(v[0]); h[1] = f2bf(v[1]); h[2] = f2bf(v[2]); h[3] = f2bf(v[3]);
    reinterpret_cast<ushort4v*>(Xbf + base)[idx] = h;
    *reinterpret_cast<ushort4v*>(&tile[n * 132 + f]) = h;
  }
  __syncthreads();
  size_t tbase = (size_t)bt * (FF * NN);
#pragma unroll
  for (int i = 0; i < 64; ++i) {
    int idx = i * 256 + tid;
    int f = idx >> 7, n = idx & 127;
    Xt[tbase + (size_t)f * NN + n0 + n] = tile[n * 132 + f];
  }
}

// ---- small 1024^3 GEMM (m97 structure): C[r][c] = sum_p A[r][p]*B[c][p] ----
__global__ __launch_bounds__(256) void gemm_s(const unsigned short* __restrict__ A,
                                              const unsigned short* __restrict__ B,
                                              unsigned short* __restrict__ C) {
  __shared__ unsigned short lA[128 * 64];
  __shared__ unsigned short lB[128 * 64];
  int r0 = ((int)blockIdx.x >> 3) << 7;
  int c0 = ((int)blockIdx.x & 7) << 7;
  int tid = threadIdx.x;
  int wave = tid >> 6, lane = tid & 63;
  int wr = wave >> 1, wc = wave & 1;
  int lr = lane & 15, g = lane >> 4;

  const unsigned short* gA = A + (size_t)r0 * 1024;
  const unsigned short* gB = B + (size_t)c0 * 1024;

  float4v acc[4][4];
#pragma unroll
  for (int a = 0; a < 4; ++a)
#pragma unroll
    for (int b = 0; b < 4; ++b) acc[a][b] = (float4v){0.f, 0.f, 0.f, 0.f};

  for (int kt = 0; kt < 16; ++kt) {
    int m0 = kt * 64;
#pragma unroll
    for (int i = 0; i < 4; ++i) {
      int id = i * 256 + tid;
      int row = id >> 3;
      int mc = (id & 7) << 3;
      int slot = (i * 256 + (tid & 192)) * 8;
      gload16(gA + (size_t)row * 1024 + m0 + mc, &lA[slot]);
      gload16(gB + (size_t)row * 1024 + m0 + mc, &lB[slot]);
    }
    __syncthreads();
#pragma unroll
    for (int kk = 0; kk < 2; ++kk) {
      short8 aF[4], bF[4];
#pragma unroll
      for (int mi = 0; mi < 4; ++mi)
        aF[mi] = *reinterpret_cast<const short8*>(
            &lA[(wr * 64 + mi * 16 + lr) * 64 + kk * 32 + g * 8]);
#pragma unroll
      for (int ni = 0; ni < 4; ++ni)
        bF[ni] = *reinterpret_cast<const short8*>(
            &lB[(wc * 64 + ni * 16 + lr) * 64 + kk * 32 + g * 8]);
#pragma unroll
      for (int mi = 0; mi < 4; ++mi)
#pragma unroll
        for (int ni = 0; ni < 4; ++ni)
          acc[mi][ni] = __builtin_amdgcn_mfma_f32_16x16x32_bf16(
              aF[mi], bF[ni], acc[mi][ni], 0, 0, 0);
    }
    __syncthreads();
  }

#pragma unroll
  for (int mi = 0; mi < 4; ++mi) {
#pragma unroll
    for (int ni = 0; ni < 4; ++ni) {
      int rr = r0 + wr * 64 + mi * 16 + g * 4;
      int cc = c0 + wc * 64 + ni * 16 + lr;
#pragma unroll
      for (int j = 0; j < 4; ++j)
        C[(size_t)(rr + j) * 1024 + cc] = f2bf(acc[mi][ni][j]);
    }
  }
}

// ---- batched chain GEMM, 256^2 tile, 32x32x16 MFMA, fragment-order LDS -----
// For power k: Zn_k[bt][n][f] = sum_m Xt[(bt,f)][m] * S^k[n][m]
// LDS chunk (tile, kf): 64 lanes x 16B, lane-linear (0 conflicts, no swizzle).
// Staging: global source per-lane scattered; LDS dest linear (rule #21).
__global__ __launch_bounds__(512, 2) void k_chain8(
    const unsigned short* __restrict__ Xt,
    const unsigned short* __restrict__ S1,
    const unsigned short* __restrict__ S2,
    const unsigned short* __restrict__ S3,
    unsigned short* __restrict__ Zn1,
    unsigned short* __restrict__ Zn2,
    unsigned short* __restrict__ Zn3) {
  extern __shared__ unsigned char lds[];   // 131072 B: 2 bufs x (A 32K + B 32K)

  // XCD-chunked mapping: all 12 blocks sharing an Xt panel on one XCD.
  int bid = blockIdx.x;
  int logical = (bid & 7) * 96 + (bid >> 3);     // 768 = 8 * 96 exact
  int cblk = logical / 12;
  int pkn = logical - cblk * 12;
  int power = pkn >> 2, nblk = pkn & 3;
  const unsigned short* Sp = (power == 0) ? S1 : ((power == 1) ? S2 : S3);
  unsigned short* Zn = (power == 0) ? Zn1 : ((power == 1) ? Zn2 : Zn3);

  int tid = threadIdx.x;
  int wave = tid >> 6, lane = tid & 63;
  int wave_m = wave >> 2, wave_n = wave & 3;
  int lo = lane & 31, hi = lane >> 5;

  // staging source element-offsets (without kt term); chunk id = j*512+tid
  unsigned asrc[4], bsrc[4];
#pragma unroll
  for (int j = 0; j < 4; ++j) {
    int id = j * 512 + tid;
    int mt = id >> 8, kf = (id >> 6) & 3;
    asrc[j] = (unsigned)(cblk * 256 + mt * 32 + lo) * 1024u + (unsigned)(kf * 16 + hi * 8);
    bsrc[j] = (unsigned)(nblk * 256 + mt * 32 + lo) * 1024u + (unsigned)(kf * 16 + hi * 8);
  }
  const unsigned stage_base = (unsigned)wave * 1024u;  // + j*8192 (wave-uniform)

  float16v acc[4][2];
#pragma unroll
  for (int a = 0; a < 4; ++a)
#pragma unroll
    for (int nt = 0; nt < 2; ++nt)
#pragma unroll
      for (int e = 0; e < 16; ++e) acc[a][nt][e] = 0.f;

  // prologue: stage ktile 0 into buf0
#pragma unroll
  for (int j = 0; j < 4; ++j) {
    gload16(Xt + asrc[j], lds + j * 8192 + stage_base);
    gload16(Sp + bsrc[j], lds + 32768 + j * 8192 + stage_base);
  }
  __syncthreads();

  for (int kt = 0; kt < 16; ++kt) {
    const unsigned bo = (unsigned)(kt & 1) << 16;
    const unsigned nbo = bo ^ 65536u;
    if (kt < 15) {
      const unsigned ko = (unsigned)(kt + 1) * 64u;
#pragma unroll
      for (int j = 0; j < 4; ++j) {
        gload16(Xt + asrc[j] + ko, lds + nbo + j * 8192 + stage_base);
        gload16(Sp + bsrc[j] + ko, lds + nbo + 32768u + j * 8192 + stage_base);
      }
    }
    const unsigned char* pa = lds + bo + wave_m * 16384 + lane * 16;
    const unsigned char* pb = lds + bo + 32768 + wave_n * 8192 + lane * 16;
    short8 bF[2][4];
#pragma unroll
    for (int nt = 0; nt < 2; ++nt)
#pragma unroll
      for (int kf = 0; kf < 4; ++kf)
        bF[nt][kf] = *reinterpret_cast<const short8*>(pb + nt * 4096 + kf * 1024);
#pragma unroll
    for (int a = 0; a < 4; ++a) {
      short8 aF[4];
#pragma unroll
      for (int kf = 0; kf < 4; ++kf)
        aF[kf] = *reinterpret_cast<const short8*>(pa + a * 4096 + kf * 1024);
      __builtin_amdgcn_s_setprio(1);
#pragma unroll
      for (int kf = 0; kf < 4; ++kf) {
        acc[a][0] = __builtin_amdgcn_mfma_f32_32x32x16_bf16(aF[kf], bF[0][kf], acc[a][0], 0, 0, 0);
        acc[a][1] = __builtin_amdgcn_mfma_f32_32x32x16_bf16(aF[kf], bF[1][kf], acc[a][1], 0, 0, 0);
      }
      __builtin_amdgcn_s_setprio(0);
    }
    __syncthreads();   // drains vmcnt(0)+lgkmcnt(0): staged kt+1 visible next iter
  }

  // epilogue: D col = lane&31 (B row = n), D row = (r&3)+8*(r>>2)+4*hi (A row = f)
  // m_global = cblk*256 + wave_m*128 + a*32 + row = bt*128 + f,
  // bt = cblk*2 + wave_m, f = a*32 + row  (wave_m folded into bt!)
  int bt = cblk * 2 + wave_m;
  size_t zbase = (size_t)bt * (NN * FF);
  int n = nblk * 256 + wave_n * 64 + lo;
#pragma unroll
  for (int a = 0; a < 4; ++a) {
#pragma unroll
    for (int nt = 0; nt < 2; ++nt) {
      size_t rowb = zbase + (size_t)(n + nt * 32) * FF;
#pragma unroll
      for (int rq = 0; rq < 4; ++rq) {
        int f = a * 32 + rq * 8 + hi * 4;
        ushort4v pk;
#pragma unroll
        for (int j = 0; j < 4; ++j) pk[j] = f2bf(acc[a][nt][rq * 4 + j]);
        *reinterpret_cast<ushort4v*>(&Zn[rowb + f]) = pk;
      }
    }
  }
}

// ---- output GEMM: Y[bt][n][o] = sum_k sum_f Z_k[bt-k][n][f] * Wk2[k][o][f] + b
__global__ __launch_bounds__(256) void k_out(const unsigned short* __restrict__ Xbf,
                                             const unsigned short* __restrict__ Zn1,
                                             const unsigned short* __restrict__ Zn2,
                                             const unsigned short* __restrict__ Zn3,
                                             const unsigned short* __restrict__ Wk2,
                                             const float* __restrict__ bias,
                                             float* __restrict__ Y) {
  __shared__ unsigned short lA[128 * 64];
  __shared__ unsigned short lB[128 * 64];
  int bid = blockIdx.x;
  int bt = bid >> 3;
  int n0 = (bid & 7) << 7;
  int t = bt & 31;
  int tid = threadIdx.x;
  int wave = tid >> 6, lane = tid & 63;
  int wr = wave >> 1, wc = wave & 1;
  int lr = lane & 15, g = lane >> 4;

  const unsigned short* Zs[4] = {Xbf, Zn1, Zn2, Zn3};

  float4v acc[4][4];
#pragma unroll
  for (int a = 0; a < 4; ++a)
#pragma unroll
    for (int b = 0; b < 4; ++b) acc[a][b] = (float4v){0.f, 0.f, 0.f, 0.f};

  for (int s = 0; s < 8; ++s) {
    int k = s >> 1;
    if (t < k) break;
    int fh = (s & 1) * 64;
    const unsigned short* gA = Zs[k] + ((size_t)(bt - k) * NN + n0) * FF;
    const unsigned short* gB = Wk2 + k * (FF * FF);
#pragma unroll
    for (int i = 0; i < 4; ++i) {
      int id = i * 256 + tid;
      int row = id >> 3;
      int fc = (id & 7) << 3;
      int slot = (i * 256 + (tid & 192)) * 8;
      gload16(gA + (size_t)row * FF + fh + fc, &lA[slot]);
      gload16(gB + (size_t)row * FF + fh + fc, &lB[slot]);
    }
    __syncthreads();
#pragma unroll
    for (int kk = 0; kk < 2; ++kk) {
      short8 aF[4], bF[4];
#pragma unroll
      for (int mi = 0; mi < 4; ++mi)
        aF[mi] = *reinterpret_cast<const short8*>(
            &lA[(wr * 64 + mi * 16 + lr) * 64 + kk * 32 + g * 8]);
#pragma unroll
      for (int ni = 0; ni < 4; ++ni)
        bF[ni] = *reinterpret_cast<const short8*>(
            &lB[(wc * 64 + ni * 16 + lr) * 64 + kk * 32 + g * 8]);
#pragma unroll
      for (int mi = 0; mi < 4; ++mi)
#pragma unroll
        for (int ni = 0; ni < 4; ++ni)
          acc[mi][ni] = __builtin_amdgcn_mfma_f32_16x16x32_bf16(
              aF[mi], bF[ni], acc[mi][ni], 0, 0, 0);
    }
    __syncthreads();
  }

  size_t obase = (size_t)bt * (NN * FF);
#pragma unroll
  for (int mi = 0; mi < 4; ++mi) {
#pragma unroll
    for (int ni = 0; ni < 4; ++ni) {
      int nloc = n0 + wr * 64 + mi * 16 + g * 4;
      int o = wc * 64 + ni * 16 + lr;
      float bv = bias[o];
#pragma unroll
      for (int j = 0; j < 4; ++j)
        Y[obase + (size_t)(nloc + j) * FF + o] = acc[mi][ni][j] + bv;
    }
  }
}

// ---- launch ----------------------------------------------------------------

extern "C" void kernel_launch(void* const* d_in, const int* in_sizes, int n_in,
                              void* d_out, int out_size, void* d_ws, size_t ws_size,
                              hipStream_t stream) {
  const float* X = (const float*)d_in[0];
  const float* S = (const float*)d_in[1];
  const float* W = (const float*)d_in[2];
  const float* bvec = (const float*)d_in[3];
  float* Y = (float*)d_out;

  char* ws = (char*)d_ws;
  const size_t ZB = (size_t)BT * NN * FF * sizeof(unsigned short);  // 32 MiB
  const size_t SB = (size_t)1024 * 1024 * sizeof(unsigned short);   // 2 MiB
  unsigned short* Xt   = (unsigned short*)(ws + 0 * ZB);
  unsigned short* Zn1  = (unsigned short*)(ws + 1 * ZB);
  unsigned short* Zn2  = (unsigned short*)(ws + 2 * ZB);
  unsigned short* Zn3  = (unsigned short*)(ws + 3 * ZB);
  unsigned short* Xbf  = (unsigned short*)(ws + 4 * ZB);
  unsigned short* Sbf  = (unsigned short*)(ws + 5 * ZB);
  unsigned short* SbfT = (unsigned short*)(ws + 5 * ZB + 1 * SB);
  unsigned short* S2   = (unsigned short*)(ws + 5 * ZB + 2 * SB);
  unsigned short* S3   = (unsigned short*)(ws + 5 * ZB + 3 * SB);
  unsigned short* Wk2  = (unsigned short*)(ws + 5 * ZB + 4 * SB);

  k_cvt_sw<<<dim3(320), dim3(256), 0, stream>>>(S, Sbf, SbfT, W, Wk2);
  k_cvt_x<<<dim3(1024), dim3(256), 0, stream>>>(X, Xbf, Xt);

  gemm_s<<<dim3(64), dim3(256), 0, stream>>>(Sbf, SbfT, S2);   // S^2
  gemm_s<<<dim3(64), dim3(256), 0, stream>>>(S2, SbfT, S3);    // S^3

  hipFuncSetAttribute((const void*)k_chain8,
                      hipFuncAttributeMaxDynamicSharedMemorySize, 131072);
  k_chain8<<<dim3(768), dim3(512), 131072, stream>>>(Xt, Sbf, S2, S3, Zn1, Zn2, Zn3);

  k_out<<<dim3(1024), dim3(256), 0, stream>>>(Xbf, Zn1, Zn2, Zn3, Wk2, bvec, Y);
}

// Round 7
// 241.511 us; speedup vs baseline: 1.0392x; 1.0392x over previous
//
#include <hip/hip_runtime.h>
#include <stdint.h>

#define BT 128
#define NN 1024
#define FF 128

typedef __attribute__((ext_vector_type(8))) short short8;
typedef __attribute__((ext_vector_type(4))) float float4v;
typedef __attribute__((ext_vector_type(16))) float float16v;
typedef __attribute__((ext_vector_type(4))) unsigned short ushort4v;

__device__ __forceinline__ unsigned short f2bf(float f) {
  uint32_t u = __builtin_bit_cast(uint32_t, f);
  u += 0x7FFFu + ((u >> 16) & 1u);   // RNE
  return (unsigned short)(u >> 16);
}

__device__ __forceinline__ void gload16(const void* g, void* l) {
  __builtin_amdgcn_global_load_lds(
      (const __attribute__((address_space(1))) uint32_t*)(g),
      (__attribute__((address_space(3))) uint32_t*)(l),
      16, 0, 0);
}

__device__ __forceinline__ void phase_enter() {
  __builtin_amdgcn_s_barrier();
  asm volatile("s_waitcnt lgkmcnt(0)" ::: "memory");
  __builtin_amdgcn_sched_barrier(0);
  __builtin_amdgcn_s_setprio(1);
}

__device__ __forceinline__ void phase_exit() {
  __builtin_amdgcn_s_setprio(0);
  __builtin_amdgcn_sched_barrier(0);
  __builtin_amdgcn_s_barrier();
  __builtin_amdgcn_sched_barrier(0);
}

// ---- fused: S -> Sbf + SbfT (blocks 0..63); W -> Wk2 (blocks 64..319) ------
__global__ __launch_bounds__(256) void k_cvt_sw(const float* __restrict__ S,
                                                unsigned short* __restrict__ Sbf,
                                                unsigned short* __restrict__ SbfT,
                                                const float* __restrict__ W,
                                                unsigned short* __restrict__ Wk2) {
  __shared__ unsigned short tile[128 * 132];
  int tid = threadIdx.x;
  if (blockIdx.x >= 64) {
    int gid = (blockIdx.x - 64) * 256 + tid;
    int k = gid >> 14, o = (gid >> 7) & 127, f = gid & 127;
    Wk2[gid] = f2bf(W[(o * 128 + f) * 4 + k]);
    return;
  }
  int r0 = ((int)blockIdx.x >> 3) << 7;
  int c0 = ((int)blockIdx.x & 7) << 7;
#pragma unroll
  for (int i = 0; i < 16; ++i) {
    int idx = i * 256 + tid;          // 4096 float4s
    int r = idx >> 5, cq = idx & 31;
    float4v v = reinterpret_cast<const float4v*>(S)[(size_t)(r0 + r) * 256 + (c0 >> 2) + cq];
    ushort4v h;
    h[0] = f2bf(v[0]); h[1] = f2bf(v[1]); h[2] = f2bf(v[2]); h[3] = f2bf(v[3]);
    *reinterpret_cast<ushort4v*>(&Sbf[(size_t)(r0 + r) * 1024 + c0 + cq * 4]) = h;
    *reinterpret_cast<ushort4v*>(&tile[r * 132 + cq * 4]) = h;
  }
  __syncthreads();
#pragma unroll
  for (int i = 0; i < 16; ++i) {
    int idx = i * 256 + tid;          // 4096 packs
    int c = idx >> 5, rq = idx & 31;
    ushort4v h;
#pragma unroll
    for (int j = 0; j < 4; ++j) h[j] = tile[(rq * 4 + j) * 132 + c];
    *reinterpret_cast<ushort4v*>(&SbfT[(size_t)(c0 + c) * 1024 + r0 + rq * 4]) = h;
  }
}

// X fp32 [bt][n][f] -> Xbf bf16 same layout, Xt bf16 [bt][f][n]
__global__ __launch_bounds__(256) void k_cvt_x(const float* __restrict__ X,
                                               unsigned short* __restrict__ Xbf,
                                               unsigned short* __restrict__ Xt) {
  __shared__ unsigned short tile[128 * 132];
  int bt = blockIdx.x >> 3;
  int n0 = (blockIdx.x & 7) << 7;
  int tid = threadIdx.x;
  size_t base = ((size_t)bt * NN + n0) * FF;
#pragma unroll
  for (int i = 0; i < 16; ++i) {
    int idx = i * 256 + tid;
    int e = idx * 4;
    int n = e >> 7, f = e & 127;
    float4v v = reinterpret_cast<const float4v*>(X + base)[idx];
    ushort4v h;
    h[0] = f2bf(v[0]); h[1] = f2bf(v[1]); h[2] = f2bf(v[2]); h[3] = f2bf(v[3]);
    reinterpret_cast<ushort4v*>(Xbf + base)[idx] = h;
    *reinterpret_cast<ushort4v*>(&tile[n * 132 + f]) = h;
  }
  __syncthreads();
  size_t tbase = (size_t)bt * (FF * NN);
#pragma unroll
  for (int i = 0; i < 64; ++i) {
    int idx = i * 256 + tid;
    int f = idx >> 7, n = idx & 127;
    Xt[tbase + (size_t)f * NN + n0 + n] = tile[n * 132 + f];
  }
}

// ---- small 1024^3 GEMM (m97 structure): C[r][c] = sum_p A[r][p]*B[c][p] ----
__global__ __launch_bounds__(256) void gemm_s(const unsigned short* __restrict__ A,
                                              const unsigned short* __restrict__ B,
                                              unsigned short* __restrict__ C) {
  __shared__ unsigned short lA[128 * 64];
  __shared__ unsigned short lB[128 * 64];
  int r0 = ((int)blockIdx.x >> 3) << 7;
  int c0 = ((int)blockIdx.x & 7) << 7;
  int tid = threadIdx.x;
  int wave = tid >> 6, lane = tid & 63;
  int wr = wave >> 1, wc = wave & 1;
  int lr = lane & 15, g = lane >> 4;

  const unsigned short* gA = A + (size_t)r0 * 1024;
  const unsigned short* gB = B + (size_t)c0 * 1024;

  float4v acc[4][4];
#pragma unroll
  for (int a = 0; a < 4; ++a)
#pragma unroll
    for (int b = 0; b < 4; ++b) acc[a][b] = (float4v){0.f, 0.f, 0.f, 0.f};

  for (int kt = 0; kt < 16; ++kt) {
    int m0 = kt * 64;
#pragma unroll
    for (int i = 0; i < 4; ++i) {
      int id = i * 256 + tid;
      int row = id >> 3;
      int mc = (id & 7) << 3;
      int slot = (i * 256 + (tid & 192)) * 8;
      gload16(gA + (size_t)row * 1024 + m0 + mc, &lA[slot]);
      gload16(gB + (size_t)row * 1024 + m0 + mc, &lB[slot]);
    }
    __syncthreads();
#pragma unroll
    for (int kk = 0; kk < 2; ++kk) {
      short8 aF[4], bF[4];
#pragma unroll
      for (int mi = 0; mi < 4; ++mi)
        aF[mi] = *reinterpret_cast<const short8*>(
            &lA[(wr * 64 + mi * 16 + lr) * 64 + kk * 32 + g * 8]);
#pragma unroll
      for (int ni = 0; ni < 4; ++ni)
        bF[ni] = *reinterpret_cast<const short8*>(
            &lB[(wc * 64 + ni * 16 + lr) * 64 + kk * 32 + g * 8]);
#pragma unroll
      for (int mi = 0; mi < 4; ++mi)
#pragma unroll
        for (int ni = 0; ni < 4; ++ni)
          acc[mi][ni] = __builtin_amdgcn_mfma_f32_16x16x32_bf16(
              aF[mi], bF[ni], acc[mi][ni], 0, 0, 0);
    }
    __syncthreads();
  }

#pragma unroll
  for (int mi = 0; mi < 4; ++mi) {
#pragma unroll
    for (int ni = 0; ni < 4; ++ni) {
      int rr = r0 + wr * 64 + mi * 16 + g * 4;
      int cc = c0 + wc * 64 + ni * 16 + lr;
#pragma unroll
      for (int j = 0; j < 4; ++j)
        C[(size_t)(rr + j) * 1024 + cc] = f2bf(acc[mi][ni][j]);
    }
  }
}

// ---- batched chain GEMM, 256^2, 32x32x16 MFMA, 4-phase counted-vmcnt -------
// Zn_k[bt][n][f] = sum_m Xt[(bt,f)][m] * S^k[n][m]
// LDS: 2 bufs x (A 32KB + B 32KB), 1KB lane-linear chunks (tile,kf). 0 conflicts.
// Staging groups (16KB = 2 gload16/wave): GA0 = A-tiles{0,1,4,5}, GA1={2,3,6,7},
// GB0 = B-tiles{0,2,4,6} (nt=0), GB1 = odd (nt=1). Issue order per kt for kt+1:
// p0:GA0 p1:GB0 p2:GB1 p3:GA1 == consumption order of kt+1 (p0 needs GA0+GB0,
// p1 needs GB1, p2 needs GA1). Counted waits: vmcnt(4) at end of p0/p1/p3.
__global__ __launch_bounds__(512, 2) void k_chain8(
    const unsigned short* __restrict__ Xt,
    const unsigned short* __restrict__ S1,
    const unsigned short* __restrict__ S2,
    const unsigned short* __restrict__ S3,
    unsigned short* __restrict__ Zn1,
    unsigned short* __restrict__ Zn2,
    unsigned short* __restrict__ Zn3) {
  extern __shared__ unsigned char lds[];   // 131072 B

  int bid = blockIdx.x;
  int logical = (bid & 7) * 96 + (bid >> 3);     // 768 = 8 * 96 exact
  int cblk = logical / 12;
  int pkn = logical - cblk * 12;
  int power = pkn >> 2, nblk = pkn & 3;
  const unsigned short* Sp = (power == 0) ? S1 : ((power == 1) ? S2 : S3);
  unsigned short* Zn = (power == 0) ? Zn1 : ((power == 1) ? Zn2 : Zn3);

  int tid = threadIdx.x;
  int wave = tid >> 6, lane = tid & 63;
  int wave_m = wave >> 2, wave_n = wave & 3;
  int lo = lane & 31, hi = lane >> 5;

  // ---- staging constants: wave stages chunks c = wave*2 + j (j=0,1) of each group
  const int i4 = wave >> 1;                    // (wave*2+j)>>2, same for j=0,1
  const int kfa = (wave & 1) << 1;             // kf = kfa + j
  const int tA0 = (i4 & 1) + ((i4 & 2) << 1);  // {0,1,4,5}[i4]
  const int tA1 = tA0 + 2;                     // {2,3,6,7}[i4]
  const int tB0 = i4 * 2, tB1 = i4 * 2 + 1;

  const unsigned colj = (unsigned)(kfa * 16 + hi * 8);   // + j*16
  const unsigned sGA0 = (unsigned)(cblk * 256 + tA0 * 32 + lo) * 1024u + colj;
  const unsigned sGA1 = (unsigned)(cblk * 256 + tA1 * 32 + lo) * 1024u + colj;
  const unsigned sGB0 = (unsigned)(nblk * 256 + tB0 * 32 + lo) * 1024u + colj;
  const unsigned sGB1 = (unsigned)(nblk * 256 + tB1 * 32 + lo) * 1024u + colj;
  const unsigned dGA0 = (unsigned)(tA0 * 4 + kfa) * 1024u;            // + j*1024
  const unsigned dGA1 = (unsigned)(tA1 * 4 + kfa) * 1024u;
  const unsigned dGB0 = 32768u + (unsigned)(tB0 * 4 + kfa) * 1024u;
  const unsigned dGB1 = 32768u + (unsigned)(tB1 * 4 + kfa) * 1024u;

  // ---- ds_read bases (chunk = (tile,kf), addr = base + kf*1024 + lane*16)
  const unsigned aoff = (unsigned)wave_m * 16384u + (unsigned)(lane << 4);  // + a*4096
  const unsigned boff = 32768u + (unsigned)wave_n * 8192u + (unsigned)(lane << 4);  // + nt*4096

  float16v acc00{}, acc01{}, acc10{}, acc11{}, acc20{}, acc21{}, acc30{}, acc31{};

  // ---- prologue: stage all 4 groups of kt=0 into buf0, FIFO order
  gload16(Xt + sGA0, lds + dGA0); gload16(Xt + sGA0 + 16, lds + dGA0 + 1024);
  gload16(Sp + sGB0, lds + dGB0); gload16(Sp + sGB0 + 16, lds + dGB0 + 1024);
  gload16(Sp + sGB1, lds + dGB1); gload16(Sp + sGB1 + 16, lds + dGB1 + 1024);
  gload16(Xt + sGA1, lds + dGA1); gload16(Xt + sGA1 + 16, lds + dGA1 + 1024);
  asm volatile("s_waitcnt vmcnt(4)" ::: "memory");   // GA0,GB0 resident
  __builtin_amdgcn_s_barrier();

#define LDSRD(base, sub, kf) \
  (*reinterpret_cast<const short8*>(lds + bo + (base) + (sub)*4096u + (kf)*1024u))

  for (int kt = 0; kt < 16; ++kt) {
    const unsigned bo = (unsigned)(kt & 1) << 16;
    const unsigned nbo = bo ^ 65536u;
    const unsigned ko = (unsigned)(kt + 1) * 64u;
    const bool st = (kt < 15);
    short8 aF0[4], aF1[4], aF2[4], aF3[4], bF0[4], bF1[4];

    // ---------- phase 0: read aF0,aF1,bF0 ; stage GA0(kt+1) ----------
#pragma unroll
    for (int kf = 0; kf < 4; ++kf) {
      aF0[kf] = LDSRD(aoff, 0, kf);
      aF1[kf] = LDSRD(aoff, 1, kf);
      bF0[kf] = LDSRD(boff, 0, kf);
    }
    if (st) {
      gload16(Xt + sGA0 + ko, lds + nbo + dGA0);
      gload16(Xt + sGA0 + ko + 16, lds + nbo + dGA0 + 1024);
      asm volatile("s_waitcnt vmcnt(4)" ::: "memory");   // GB1(kt) resident
    } else {
      asm volatile("s_waitcnt vmcnt(2)" ::: "memory");
    }
    phase_enter();
#pragma unroll
    for (int kf = 0; kf < 4; ++kf) {
      acc00 = __builtin_amdgcn_mfma_f32_32x32x16_bf16(aF0[kf], bF0[kf], acc00, 0, 0, 0);
      acc10 = __builtin_amdgcn_mfma_f32_32x32x16_bf16(aF1[kf], bF0[kf], acc10, 0, 0, 0);
    }
    phase_exit();

    // ---------- phase 1: read bF1 ; stage GB0(kt+1) ----------
#pragma unroll
    for (int kf = 0; kf < 4; ++kf) bF1[kf] = LDSRD(boff, 1, kf);
    if (st) {
      gload16(Sp + sGB0 + ko, lds + nbo + dGB0);
      gload16(Sp + sGB0 + ko + 16, lds + nbo + dGB0 + 1024);
      asm volatile("s_waitcnt vmcnt(4)" ::: "memory");   // GA1(kt) resident
    } else {
      asm volatile("s_waitcnt vmcnt(0)" ::: "memory");
    }
    phase_enter();
#pragma unroll
    for (int kf = 0; kf < 4; ++kf) {
      acc01 = __builtin_amdgcn_mfma_f32_32x32x16_bf16(aF0[kf], bF1[kf], acc01, 0, 0, 0);
      acc11 = __builtin_amdgcn_mfma_f32_32x32x16_bf16(aF1[kf], bF1[kf], acc11, 0, 0, 0);
    }
    phase_exit();

    // ---------- phase 2: read aF2,aF3 ; stage GB1(kt+1) ; no vm wait ----------
#pragma unroll
    for (int kf = 0; kf < 4; ++kf) {
      aF2[kf] = LDSRD(aoff, 2, kf);
      aF3[kf] = LDSRD(aoff, 3, kf);
    }
    if (st) {
      gload16(Sp + sGB1 + ko, lds + nbo + dGB1);
      gload16(Sp + sGB1 + ko + 16, lds + nbo + dGB1 + 1024);
    }
    phase_enter();
#pragma unroll
    for (int kf = 0; kf < 4; ++kf) {
      acc20 = __builtin_amdgcn_mfma_f32_32x32x16_bf16(aF2[kf], bF0[kf], acc20, 0, 0, 0);
      acc30 = __builtin_amdgcn_mfma_f32_32x32x16_bf16(aF3[kf], bF0[kf], acc30, 0, 0, 0);
    }
    phase_exit();

    // ---------- phase 3: no reads ; stage GA1(kt+1) ----------
    if (st) {
      gload16(Xt + sGA1 + ko, lds + nbo + dGA1);
      gload16(Xt + sGA1 + ko + 16, lds + nbo + dGA1 + 1024);
      asm volatile("s_waitcnt vmcnt(4)" ::: "memory");   // GA0,GB0(kt+1) resident
    }
    phase_enter();
#pragma unroll
    for (int kf = 0; kf < 4; ++kf) {
      acc21 = __builtin_amdgcn_mfma_f32_32x32x16_bf16(aF2[kf], bF1[kf], acc21, 0, 0, 0);
      acc31 = __builtin_amdgcn_mfma_f32_32x32x16_bf16(aF3[kf], bF1[kf], acc31, 0, 0, 0);
    }
    phase_exit();
  }
#undef LDSRD

  // ---- epilogue: bt = cblk*2 + wave_m, f = a*32 + rq*8 + hi*4 (R5-verified)
  int bt = cblk * 2 + wave_m;
  size_t zbase = (size_t)bt * (NN * FF);
  int n = nblk * 256 + wave_n * 64 + lo;
  const float16v* accs[4][2] = {{&acc00, &acc01}, {&acc10, &acc11},
                                {&acc20, &acc21}, {&acc30, &acc31}};
#pragma unroll
  for (int a = 0; a < 4; ++a) {
#pragma unroll
    for (int nt = 0; nt < 2; ++nt) {
      const float16v av = *accs[a][nt];
      size_t rowb = zbase + (size_t)(n + nt * 32) * FF;
#pragma unroll
      for (int rq = 0; rq < 4; ++rq) {
        int f = a * 32 + rq * 8 + hi * 4;
        ushort4v pk;
#pragma unroll
        for (int j = 0; j < 4; ++j) pk[j] = f2bf(av[rq * 4 + j]);
        *reinterpret_cast<ushort4v*>(&Zn[rowb + f]) = pk;
      }
    }
  }
}

// ---- output GEMM: Y[bt][n][o] = sum_k sum_f Z_k[bt-k][n][f] * Wk2[k][o][f] + b
__global__ __launch_bounds__(256) void k_out(const unsigned short* __restrict__ Xbf,
                                             const unsigned short* __restrict__ Zn1,
                                             const unsigned short* __restrict__ Zn2,
                                             const unsigned short* __restrict__ Zn3,
                                             const unsigned short* __restrict__ Wk2,
                                             const float* __restrict__ bias,
                                             float* __restrict__ Y) {
  __shared__ unsigned short lA[128 * 64];
  __shared__ unsigned short lB[128 * 64];
  int bid = blockIdx.x;
  int bt = bid >> 3;
  int n0 = (bid & 7) << 7;
  int t = bt & 31;
  int tid = threadIdx.x;
  int wave = tid >> 6, lane = tid & 63;
  int wr = wave >> 1, wc = wave & 1;
  int lr = lane & 15, g = lane >> 4;

  const unsigned short* Zs[4] = {Xbf, Zn1, Zn2, Zn3};

  float4v acc[4][4];
#pragma unroll
  for (int a = 0; a < 4; ++a)
#pragma unroll
    for (int b = 0; b < 4; ++b) acc[a][b] = (float4v){0.f, 0.f, 0.f, 0.f};

  for (int s = 0; s < 8; ++s) {
    int k = s >> 1;
    if (t < k) break;
    int fh = (s & 1) * 64;
    const unsigned short* gA = Zs[k] + ((size_t)(bt - k) * NN + n0) * FF;
    const unsigned short* gB = Wk2 + k * (FF * FF);
#pragma unroll
    for (int i = 0; i < 4; ++i) {
      int id = i * 256 + tid;
      int row = id >> 3;
      int fc = (id & 7) << 3;
      int slot = (i * 256 + (tid & 192)) * 8;
      gload16(gA + (size_t)row * FF + fh + fc, &lA[slot]);
      gload16(gB + (size_t)row * FF + fh + fc, &lB[slot]);
    }
    __syncthreads();
#pragma unroll
    for (int kk = 0; kk < 2; ++kk) {
      short8 aF[4], bF[4];
#pragma unroll
      for (int mi = 0; mi < 4; ++mi)
        aF[mi] = *reinterpret_cast<const short8*>(
            &lA[(wr * 64 + mi * 16 + lr) * 64 + kk * 32 + g * 8]);
#pragma unroll
      for (int ni = 0; ni < 4; ++ni)
        bF[ni] = *reinterpret_cast<const short8*>(
            &lB[(wc * 64 + ni * 16 + lr) * 64 + kk * 32 + g * 8]);
#pragma unroll
      for (int mi = 0; mi < 4; ++mi)
#pragma unroll
        for (int ni = 0; ni < 4; ++ni)
          acc[mi][ni] = __builtin_amdgcn_mfma_f32_16x16x32_bf16(
              aF[mi], bF[ni], acc[mi][ni], 0, 0, 0);
    }
    __syncthreads();
  }

  size_t obase = (size_t)bt * (NN * FF);
#pragma unroll
  for (int mi = 0; mi < 4; ++mi) {
#pragma unroll
    for (int ni = 0; ni < 4; ++ni) {
      int nloc = n0 + wr * 64 + mi * 16 + g * 4;
      int o = wc * 64 + ni * 16 + lr;
      float bv = bias[o];
#pragma unroll
      for (int j = 0; j < 4; ++j)
        Y[obase + (size_t)(nloc + j) * FF + o] = acc[mi][ni][j] + bv;
    }
  }
}

// ---- launch ----------------------------------------------------------------

extern "C" void kernel_launch(void* const* d_in, const int* in_sizes, int n_in,
                              void* d_out, int out_size, void* d_ws, size_t ws_size,
                              hipStream_t stream) {
  const float* X = (const float*)d_in[0];
  const float* S = (const float*)d_in[1];
  const float* W = (const float*)d_in[2];
  const float* bvec = (const float*)d_in[3];
  float* Y = (float*)d_out;

  char* ws = (char*)d_ws;
  const size_t ZB = (size_t)BT * NN * FF * sizeof(unsigned short);  // 32 MiB
  const size_t SB = (size_t)1024 * 1024 * sizeof(unsigned short);   // 2 MiB
  unsigned short* Xt   = (unsigned short*)(ws + 0 * ZB);
  unsigned short* Zn1  = (unsigned short*)(ws + 1 * ZB);
  unsigned short* Zn2  = (unsigned short*)(ws + 2 * ZB);
  unsigned short* Zn3  = (unsigned short*)(ws + 3 * ZB);
  unsigned short* Xbf  = (unsigned short*)(ws + 4 * ZB);
  unsigned short* Sbf  = (unsigned short*)(ws + 5 * ZB);
  unsigned short* SbfT = (unsigned short*)(ws + 5 * ZB + 1 * SB);
  unsigned short* S2   = (unsigned short*)(ws + 5 * ZB + 2 * SB);
  unsigned short* S3   = (unsigned short*)(ws + 5 * ZB + 3 * SB);
  unsigned short* Wk2  = (unsigned short*)(ws + 5 * ZB + 4 * SB);

  k_cvt_sw<<<dim3(320), dim3(256), 0, stream>>>(S, Sbf, SbfT, W, Wk2);
  k_cvt_x<<<dim3(1024), dim3(256), 0, stream>>>(X, Xbf, Xt);

  gemm_s<<<dim3(64), dim3(256), 0, stream>>>(Sbf, SbfT, S2);   // S^2
  gemm_s<<<dim3(64), dim3(256), 0, stream>>>(S2, SbfT, S3);    // S^3

  hipError_t _e = hipFuncSetAttribute((const void*)k_chain8,
                      hipFuncAttributeMaxDynamicSharedMemorySize, 131072);
  (void)_e;
  k_chain8<<<dim3(768), dim3(512), 131072, stream>>>(Xt, Sbf, S2, S3, Zn1, Zn2, Zn3);

  k_out<<<dim3(1024), dim3(256), 0, stream>>>(Xbf, Zn1, Zn2, Zn3, Wk2, bvec, Y);
}